// Round 10
// baseline (341.923 us; speedup 1.0000x reference)
//
#include <hip/hip_runtime.h>
#include <hip/hip_bf16.h>

// SAGEConv(mean), 7-dispatch pipeline, zero global atomics:
//   k_prep    = bucket histogram (LDS atomics) + x->bf16 cast, fused
//   k_bscan   = 1-block: bucket totals + bases + cnt->absolute cursors
//   k_bscatter= scatter packed (dst&511)<<17|src into bucket segments
//   k_bucket  = per-bucket LDS counting sort + gather-mean -> mh (no CSR!)
//   k_fused   = MFMA [mean|x]@[Wl;Wr]^T + L2norm + ReLU + BN partials
//   k_stats   = reduce BN partials
//   k_out     = BN-fold + FC
// N=100000, E=1200000, F=H=64, C=16.
//
// Lessons: R4/R5/R7/R8 — device-scope atomics run at the shared coherence
// point (~24.5 G atomics/s, ~32B sector each); privatization can't help;
// only LDS atomics are cheap. R9→R10 — per-dispatch overhead ~5us: fuse
// launches; rowptr/colv were never needed downstream of the bucket sort.

typedef __attribute__((ext_vector_type(8))) short short8;   // 8 bf16
typedef __attribute__((ext_vector_type(4))) float f32x4;

__device__ __forceinline__ unsigned short f2bf(float f) {
    unsigned int u = __builtin_bit_cast(unsigned int, f);
    u += 0x7FFFu + ((u >> 16) & 1u);
    return (unsigned short)(u >> 16);
}
__device__ __forceinline__ float bf2f(unsigned short s) {
    return __builtin_bit_cast(float, ((unsigned int)s) << 16);
}
__device__ __forceinline__ float bflo(unsigned int w) {
    return __builtin_bit_cast(float, w << 16);
}
__device__ __forceinline__ float bfhi(unsigned int w) {
    return __builtin_bit_cast(float, w & 0xFFFF0000u);
}

#define CHUNK 8192
#define MAXSEG 8192

// ---------------- k_prep: blocks [0,NBLK) = bucket hist; rest = x->bf16 cast
__global__ __launch_bounds__(256) void k_prep(const int* __restrict__ eidx,
                                              int* __restrict__ cnt,
                                              const float4* __restrict__ x4,
                                              ushort4* __restrict__ xbf,
                                              int E, int NB, int NBLK,
                                              int n4, int do_x) {
    __shared__ int lh[256];
    const int tid = threadIdx.x;
    if ((int)blockIdx.x < NBLK) {
        lh[tid] = 0;
        __syncthreads();
        const int base = blockIdx.x * CHUNK;
        for (int i = tid; i < CHUNK; i += 256) {
            int e = base + i;
            if (e < E) atomicAdd(&lh[eidx[E + e] >> 9], 1);
        }
        __syncthreads();
        if (tid < NB) cnt[(size_t)blockIdx.x * NB + tid] = lh[tid];
    } else if (do_x) {
        int t = ((int)blockIdx.x - NBLK) * 256 + tid;
        if (t < n4) {
            float4 v = x4[t];
            xbf[t] = make_ushort4(f2bf(v.x), f2bf(v.y), f2bf(v.z), f2bf(v.w));
        }
    }
}

// ---------------- k_bscan: one block. totals -> bbase; cnt -> absolute cursors
__global__ __launch_bounds__(256) void k_bscan(int* __restrict__ cnt,
                                               int* __restrict__ bbase,
                                               int NBLK, int NB, int E) {
    __shared__ int swv[4];
    const int t = threadIdx.x;
    int tot = 0;
    if (t < NB)
        for (int c = 0; c < NBLK; ++c) tot += cnt[(size_t)c * NB + t];
    const int lane = t & 63, wid = t >> 6;
    int s = tot;
#pragma unroll
    for (int off = 1; off < 64; off <<= 1) {
        int tt = __shfl_up(s, off);
        if (lane >= off) s += tt;
    }
    if (lane == 63) swv[wid] = s;
    __syncthreads();
    if (t == 0) {
        int a = 0;
#pragma unroll
        for (int w = 0; w < 4; ++w) { int tt = swv[w]; swv[w] = a; a += tt; }
    }
    __syncthreads();
    int base = s - tot + swv[wid];
    if (t < NB) {
        bbase[t] = base;
        int run = base;
        for (int c = 0; c < NBLK; ++c) {
            int v = cnt[(size_t)c * NB + t];
            cnt[(size_t)c * NB + t] = run;
            run += v;
        }
    }
    if (t == 0) bbase[NB] = E;
}

// ---------------- k_bscatter: packed edges into bucket segments (LDS cursors)
__global__ __launch_bounds__(256) void k_bscatter(const int* __restrict__ eidx,
                                                  const int* __restrict__ cnt,
                                                  unsigned int* __restrict__ ebuf,
                                                  int E, int NB) {
    __shared__ int cur[256];
    const int tid = threadIdx.x;
    if (tid < NB) cur[tid] = cnt[(size_t)blockIdx.x * NB + tid];
    __syncthreads();
    const int base = blockIdx.x * CHUNK;
    for (int i = tid; i < CHUNK; i += 256) {
        int e = base + i;
        if (e < E) {
            int d = eidx[E + e];
            int s = eidx[e];
            int p = atomicAdd(&cur[d >> 9], 1);
            ebuf[p] = (unsigned int)s | ((unsigned int)(d & 511) << 17);
        }
    }
}

// ---------------- k_bucket: per-bucket LDS sort + gather-mean -> mh
// 16 lanes/edge-or-node: lane l owns features 4l..4l+3 (one uint2 = 4 bf16).
__global__ __launch_bounds__(256) void k_bucket(const unsigned int* __restrict__ ebuf,
                                                const int* __restrict__ bbase,
                                                const uint2* __restrict__ xbf2,
                                                const float4* __restrict__ x4,
                                                uint2* __restrict__ mh2,
                                                int N, int use_bf) {
    __shared__ int lh[512];     // per-node counts
    __shared__ int lcur[512];   // scan -> insert cursor -> end position
    __shared__ int srcl[MAXSEG];
    __shared__ int swv[4];
    const int b = blockIdx.x;
    const int tid = threadIdx.x;
    const int segb = bbase[b], sege = bbase[b + 1];
    const int seg = sege - segb;
    lh[2 * tid] = 0;
    lh[2 * tid + 1] = 0;
    __syncthreads();
    for (int i = segb + tid; i < sege; i += 256)
        atomicAdd(&lh[ebuf[i] >> 17], 1);
    __syncthreads();

    const bool fast = (seg <= MAXSEG);
    if (fast) {
        // exclusive scan of lh into lcur (512 entries, 2/thread)
        int a0 = lh[2 * tid], a1 = lh[2 * tid + 1];
        int ts = a0 + a1;
        const int lane = tid & 63, wid = tid >> 6;
        int s = ts;
#pragma unroll
        for (int off = 1; off < 64; off <<= 1) {
            int tt = __shfl_up(s, off);
            if (lane >= off) s += tt;
        }
        if (lane == 63) swv[wid] = s;
        __syncthreads();
        if (tid == 0) {
            int a = 0;
#pragma unroll
            for (int w = 0; w < 4; ++w) { int tt = swv[w]; swv[w] = a; a += tt; }
        }
        __syncthreads();
        int excl = s - ts + swv[wid];
        lcur[2 * tid] = excl;
        lcur[2 * tid + 1] = excl + a0;
        __syncthreads();
        for (int i = segb + tid; i < sege; i += 256) {
            unsigned int u = ebuf[i];
            int p = atomicAdd(&lcur[u >> 17], 1);
            srcl[p] = (int)(u & 0x1FFFFu);
        }
        __syncthreads();
        // after insertion lcur[nl] == end; beg = end - lh[nl]
    }

    const int g = tid >> 4;     // 16 groups
    const int l = tid & 15;
    for (int k = 0; k < 32; ++k) {
        const int nl = g * 32 + k;
        const int node = b * 512 + nl;
        if (node >= N) break;
        const int dg = lh[nl];
        float a0 = 0.f, a1 = 0.f, a2 = 0.f, a3 = 0.f;
        if (fast) {
            const int end = lcur[nl];
            int p = end - dg;
            for (; p + 2 <= end; p += 2) {
                int s0 = srcl[p], s1 = srcl[p + 1];
                if (use_bf) {
                    uint2 v0 = xbf2[(size_t)s0 * 16 + l];
                    uint2 v1 = xbf2[(size_t)s1 * 16 + l];
                    a0 += bflo(v0.x) + bflo(v1.x);
                    a1 += bfhi(v0.x) + bfhi(v1.x);
                    a2 += bflo(v0.y) + bflo(v1.y);
                    a3 += bfhi(v0.y) + bfhi(v1.y);
                } else {
                    float4 v0 = x4[(size_t)s0 * 16 + l];
                    float4 v1 = x4[(size_t)s1 * 16 + l];
                    a0 += v0.x + v1.x; a1 += v0.y + v1.y;
                    a2 += v0.z + v1.z; a3 += v0.w + v1.w;
                }
            }
            if (p < end) {
                int s0 = srcl[p];
                if (use_bf) {
                    uint2 v0 = xbf2[(size_t)s0 * 16 + l];
                    a0 += bflo(v0.x); a1 += bfhi(v0.x);
                    a2 += bflo(v0.y); a3 += bfhi(v0.y);
                } else {
                    float4 v0 = x4[(size_t)s0 * 16 + l];
                    a0 += v0.x; a1 += v0.y; a2 += v0.z; a3 += v0.w;
                }
            }
        } else {
            // pathological bucket (never for this input): linear scan, correct
            for (int i = segb; i < sege; ++i) {
                unsigned int u = ebuf[i];
                if ((int)(u >> 17) == nl) {
                    int s0 = (int)(u & 0x1FFFFu);
                    if (use_bf) {
                        uint2 v0 = xbf2[(size_t)s0 * 16 + l];
                        a0 += bflo(v0.x); a1 += bfhi(v0.x);
                        a2 += bflo(v0.y); a3 += bfhi(v0.y);
                    } else {
                        float4 v0 = x4[(size_t)s0 * 16 + l];
                        a0 += v0.x; a1 += v0.y; a2 += v0.z; a3 += v0.w;
                    }
                }
            }
        }
        float inv = 1.0f / fmaxf((float)dg, 1.0f);
        unsigned int lo0 = f2bf(a0 * inv), hi0 = f2bf(a1 * inv);
        unsigned int lo1 = f2bf(a2 * inv), hi1 = f2bf(a3 * inv);
        uint2 o;
        o.x = lo0 | (hi0 << 16);
        o.y = lo1 | (hi1 << 16);
        mh2[(size_t)node * 16 + l] = o;
    }
}

// --------- k_fused: MFMA [mean|x]@[Wl;Wr]^T + bl, L2norm, ReLU, BN partials.
// 256 nodes/block (4 tiles per wave). Root operand from xbf (bf16) when avail.
__global__ __launch_bounds__(256) void k_fused(
        const float* __restrict__ x,
        const unsigned short* __restrict__ xbf, int use_bf,
        const float* __restrict__ Wl, const float* __restrict__ bl,
        const float* __restrict__ Wr,
        unsigned short* __restrict__ mh,   // in: bf16 mean; out: bf16 h
        float* __restrict__ pstats, int N) {
    __shared__ float sRed[4][128];

    const int tid = threadIdx.x;
    const int wid = tid >> 6;
    const int lane = tid & 63;
    const int l15 = lane & 15;
    const int quad = lane >> 4;

    short8 bfrag[4][4];
#pragma unroll
    for (int c = 0; c < 4; ++c) {
#pragma unroll
        for (int f = 0; f < 4; ++f) {
            const int n = f * 16 + l15;
            const float* wsrc = (c < 2)
                ? (Wl + (size_t)n * 64 + c * 32 + quad * 8)
                : (Wr + (size_t)n * 64 + (c - 2) * 32 + quad * 8);
            float4 w0 = *(const float4*)wsrc;
            float4 w1 = *(const float4*)(wsrc + 4);
            union { short8 v; unsigned short u[8]; } pk;
            pk.u[0] = f2bf(w0.x); pk.u[1] = f2bf(w0.y);
            pk.u[2] = f2bf(w0.z); pk.u[3] = f2bf(w0.w);
            pk.u[4] = f2bf(w1.x); pk.u[5] = f2bf(w1.y);
            pk.u[6] = f2bf(w1.z); pk.u[7] = f2bf(w1.w);
            bfrag[c][f] = pk.v;
        }
    }

    float blv[4];
#pragma unroll
    for (int f = 0; f < 4; ++f) blv[f] = bl[f * 16 + l15];

    float psum[4] = {0.f, 0.f, 0.f, 0.f};
    float psq[4] = {0.f, 0.f, 0.f, 0.f};

    for (int t4 = 0; t4 < 4; ++t4) {
        const int tbase = blockIdx.x * 256 + wid * 64 + t4 * 16;
        const int mrow = tbase + l15;
        const int mld = (mrow < N) ? mrow : (N - 1);
        f32x4 acc[4] = {{0.f, 0.f, 0.f, 0.f}, {0.f, 0.f, 0.f, 0.f},
                        {0.f, 0.f, 0.f, 0.f}, {0.f, 0.f, 0.f, 0.f}};
#pragma unroll
        for (int c = 0; c < 2; ++c) {
            short8 a = *(const short8*)(mh + (size_t)mld * 64 + c * 32 + quad * 8);
#pragma unroll
            for (int f = 0; f < 4; ++f)
                acc[f] = __builtin_amdgcn_mfma_f32_16x16x32_bf16(a, bfrag[c][f], acc[f], 0, 0, 0);
        }
        if (use_bf) {
#pragma unroll
            for (int c = 0; c < 2; ++c) {
                short8 a = *(const short8*)(xbf + (size_t)mld * 64 + c * 32 + quad * 8);
#pragma unroll
                for (int f = 0; f < 4; ++f)
                    acc[f] = __builtin_amdgcn_mfma_f32_16x16x32_bf16(a, bfrag[c + 2][f], acc[f], 0, 0, 0);
            }
        } else {
#pragma unroll
            for (int c = 0; c < 2; ++c) {
                const float* xp = x + (size_t)mld * 64 + c * 32 + quad * 8;
                float4 a0 = *(const float4*)xp;
                float4 a1 = *(const float4*)(xp + 4);
                union { short8 v; unsigned short u[8]; } pk;
                pk.u[0] = f2bf(a0.x); pk.u[1] = f2bf(a0.y);
                pk.u[2] = f2bf(a0.z); pk.u[3] = f2bf(a0.w);
                pk.u[4] = f2bf(a1.x); pk.u[5] = f2bf(a1.y);
                pk.u[6] = f2bf(a1.z); pk.u[7] = f2bf(a1.w);
#pragma unroll
                for (int f = 0; f < 4; ++f)
                    acc[f] = __builtin_amdgcn_mfma_f32_16x16x32_bf16(pk.v, bfrag[c + 2][f], acc[f], 0, 0, 0);
            }
        }

#pragma unroll
        for (int reg = 0; reg < 4; ++reg) {
            const int node = tbase + quad * 4 + reg;
            float hv[4];
            float ss = 0.f;
#pragma unroll
            for (int f = 0; f < 4; ++f) {
                hv[f] = acc[f][reg] + blv[f];
                ss += hv[f] * hv[f];
            }
            ss += __shfl_xor(ss, 1);
            ss += __shfl_xor(ss, 2);
            ss += __shfl_xor(ss, 4);
            ss += __shfl_xor(ss, 8);
            float sc = 1.0f / fmaxf(sqrtf(ss), 1e-12f);
            if (node < N) {
#pragma unroll
                for (int f = 0; f < 4; ++f) {
                    float r = fmaxf(hv[f] * sc, 0.f);
                    unsigned short rb = f2bf(r);
                    float e = bf2f(rb);
                    mh[(size_t)node * 64 + f * 16 + l15] = rb;
                    psum[f] += e;
                    psq[f] += e * e;
                }
            }
        }
    }

#pragma unroll
    for (int f = 0; f < 4; ++f) {
        psum[f] += __shfl_xor(psum[f], 16);
        psum[f] += __shfl_xor(psum[f], 32);
        psq[f] += __shfl_xor(psq[f], 16);
        psq[f] += __shfl_xor(psq[f], 32);
    }
    if (lane < 16) {
#pragma unroll
        for (int f = 0; f < 4; ++f) {
            sRed[wid][f * 16 + l15] = psum[f];
            sRed[wid][64 + f * 16 + l15] = psq[f];
        }
    }
    __syncthreads();
    if (tid < 128) {
        float v = sRed[0][tid] + sRed[1][tid] + sRed[2][tid] + sRed[3][tid];
        pstats[(size_t)blockIdx.x * 128 + tid] = v;
    }
}

// ---------------------------------------------- reduce per-block BN partials
__global__ __launch_bounds__(64) void k_stats(const float* __restrict__ pstats,
                                              float* __restrict__ stats, int nblk) {
    int col = blockIdx.x;
    int l = threadIdx.x;
    float s = 0.f;
    for (int r = l; r < nblk; r += 64) s += pstats[(size_t)r * 128 + col];
    s += __shfl_xor(s, 1);
    s += __shfl_xor(s, 2);
    s += __shfl_xor(s, 4);
    s += __shfl_xor(s, 8);
    s += __shfl_xor(s, 16);
    s += __shfl_xor(s, 32);
    if (l == 0) stats[col] = s;
}

// ---------------------------------------------------------------- BN-fold + FC
__global__ __launch_bounds__(256) void k_out(
        const unsigned short* __restrict__ h, const float* __restrict__ stats,
        const float* __restrict__ gamma, const float* __restrict__ beta,
        const float* __restrict__ Wfc, const float* __restrict__ bfc,
        float* __restrict__ out, int N) {
    __shared__ float sWm[64 * 16];
    __shared__ float sShift[64];
    __shared__ float sBase[16];
    const int tid = threadIdx.x;
    const float invN = 1.0f / (float)N;
    if (tid < 64) {
        float mu = stats[tid] * invN;
        float var = stats[64 + tid] * invN - mu * mu;
        float sc = gamma[tid] / sqrtf(var + 1e-5f);
        sShift[tid] = beta[tid] - mu * sc;
#pragma unroll
        for (int c = 0; c < 16; ++c) sWm[tid * 16 + c] = Wfc[c * 64 + tid] * sc;
    }
    __syncthreads();
    if (tid < 16) {
        float b = bfc[tid];
#pragma unroll
        for (int j = 0; j < 64; ++j) b += sShift[j] * Wfc[tid * 64 + j];
        sBase[tid] = b;
    }
    __syncthreads();
    int g = blockIdx.x * 256 + tid;
    int n = g >> 4;
    int c = g & 15;
    if (n >= N) return;
    const ushort4* h4 = (const ushort4*)(h + (size_t)n * 64);
    float acc = sBase[c];
#pragma unroll
    for (int jq = 0; jq < 16; ++jq) {
        ushort4 v = h4[jq];
        acc += bf2f(v.x) * sWm[(jq * 4 + 0) * 16 + c];
        acc += bf2f(v.y) * sWm[(jq * 4 + 1) * 16 + c];
        acc += bf2f(v.z) * sWm[(jq * 4 + 2) * 16 + c];
        acc += bf2f(v.w) * sWm[(jq * 4 + 3) * 16 + c];
    }
    out[(size_t)n * 16 + c] = acc;
}

extern "C" void kernel_launch(void* const* d_in, const int* in_sizes, int n_in,
                              void* d_out, int out_size, void* d_ws, size_t ws_size,
                              hipStream_t stream) {
    const int* eidx = (const int*)d_in[0];
    const float* x = (const float*)d_in[1];
    const float* Wl = (const float*)d_in[2];
    const float* bl = (const float*)d_in[3];
    const float* Wr = (const float*)d_in[4];
    const float* gamma = (const float*)d_in[5];
    const float* beta = (const float*)d_in[6];
    const float* Wfc = (const float*)d_in[7];
    const float* bfc = (const float*)d_in[8];
    float* out = (float*)d_out;

    const int E = in_sizes[0] / 2;
    const int N = in_sizes[1] / 64;
    const int NB = (N + 511) >> 9;               // <=256 for N<=131072
    const int NBLK = (E + CHUNK - 1) / CHUNK;    // <=256 for E<=2.09M
    const int fb2 = (N + 255) / 256;             // k_fused blocks
    const int n4 = N * 16;

    // layout (4B words):
    int* cnt = (int*)d_ws;                                     // NBLK*NB
    int* bbase = cnt + (size_t)NBLK * NB;                      // NB+1
    float* pstats = (float*)(bbase + NB + 1);                  // fb2*128
    float* stats = pstats + (size_t)fb2 * 128;                 // 128
    unsigned int* ebuf = (unsigned int*)(stats + 128);         // E
    unsigned short* mh = (unsigned short*)(ebuf + E);          // N*64 bf16
    unsigned short* xbf = mh + (size_t)N * 64;                 // N*64 bf16 opt

    size_t need_bf = (size_t)((char*)(xbf + (size_t)N * 64) - (char*)d_ws);
    const int use_bf = (ws_size >= need_bf) ? 1 : 0;

    int cbl = use_bf ? (n4 + 255) / 256 : 0;
    k_prep<<<NBLK + cbl, 256, 0, stream>>>(eidx, cnt, (const float4*)x,
                                           (ushort4*)xbf, E, NB, NBLK, n4, use_bf);
    k_bscan<<<1, 256, 0, stream>>>(cnt, bbase, NBLK, NB, E);
    k_bscatter<<<NBLK, 256, 0, stream>>>(eidx, cnt, ebuf, E, NB);
    k_bucket<<<NB, 256, 0, stream>>>(ebuf, bbase, (const uint2*)xbf,
                                     (const float4*)x, (uint2*)mh, N, use_bf);
    k_fused<<<fb2, 256, 0, stream>>>(x, xbf, use_bf, Wl, bl, Wr, mh, pstats, N);
    k_stats<<<128, 64, 0, stream>>>(pstats, stats, fb2);

    int oblocks = (int)(((size_t)N * 16 + 255) / 256);
    k_out<<<oblocks, 256, 0, stream>>>(mh, stats, gamma, beta, Wfc, bfc, out, N);
}

// Round 11
// 258.479 us; speedup vs baseline: 1.3228x; 1.3228x over previous
//
#include <hip/hip_runtime.h>
#include <hip/hip_bf16.h>

// SAGEConv(mean), 8-dispatch pipeline, zero global atomics:
//   k_prep    = bucket histogram (LDS atomics) + x->bf16 cast, fused
//   k_bscan   = 1-block: bucket bases + cnt->absolute cursors + rowptr[N]
//   k_bscatter= scatter packed (dst&511)<<17|src into bucket segments
//   k_bfinal  = per-bucket LDS counting sort -> rowptr + colv
//   k_gather  = 16-lanes/node CSR gather-mean (6250 blocks: TLP is king)
//   k_fused   = MFMA [mean|x]@[Wl;Wr]^T + L2norm + ReLU + BN partials
//   k_stats / k_out
// N=100000, E=1200000, F=H=64, C=16.
//
// Lessons: R4/R5/R7/R8 — device-scope atomics run at the shared coherence
// point (~24.5 G atomics/s); only LDS atomics are cheap. R10 — fusing the
// random gather into per-bucket blocks (196 blocks, 7.9% occupancy) cost
// 132us: the gather needs ~25k waves of TLP. Never shrink its grid.

typedef __attribute__((ext_vector_type(8))) short short8;   // 8 bf16
typedef __attribute__((ext_vector_type(4))) float f32x4;

__device__ __forceinline__ unsigned short f2bf(float f) {
    unsigned int u = __builtin_bit_cast(unsigned int, f);
    u += 0x7FFFu + ((u >> 16) & 1u);
    return (unsigned short)(u >> 16);
}
__device__ __forceinline__ float bf2f(unsigned short s) {
    return __builtin_bit_cast(float, ((unsigned int)s) << 16);
}

#define CHUNK 8192

// ---------------- k_prep: blocks [0,NBLK) = bucket hist; rest = x->bf16 cast
__global__ __launch_bounds__(256) void k_prep(const int* __restrict__ eidx,
                                              int* __restrict__ cnt,
                                              const float4* __restrict__ x4,
                                              ushort4* __restrict__ xbf,
                                              int E, int NB, int NBLK,
                                              int n4, int do_x) {
    __shared__ int lh[256];
    const int tid = threadIdx.x;
    if ((int)blockIdx.x < NBLK) {
        lh[tid] = 0;
        __syncthreads();
        const int base = blockIdx.x * CHUNK;
        for (int i = tid; i < CHUNK; i += 256) {
            int e = base + i;
            if (e < E) atomicAdd(&lh[eidx[E + e] >> 9], 1);
        }
        __syncthreads();
        if (tid < NB) cnt[(size_t)blockIdx.x * NB + tid] = lh[tid];
    } else if (do_x) {
        int t = ((int)blockIdx.x - NBLK) * 256 + tid;
        if (t < n4) {
            float4 v = x4[t];
            xbf[t] = make_ushort4(f2bf(v.x), f2bf(v.y), f2bf(v.z), f2bf(v.w));
        }
    }
}

// -------- k_bscan: one block. bucket bases -> bbase; cnt -> absolute cursors
__global__ __launch_bounds__(256) void k_bscan(int* __restrict__ cnt,
                                               int* __restrict__ bbase,
                                               int* __restrict__ rowptr,
                                               int NBLK, int NB, int N, int E) {
    __shared__ int swv[4];
    const int t = threadIdx.x;
    int tot = 0;
    if (t < NB)
        for (int c = 0; c < NBLK; ++c) tot += cnt[(size_t)c * NB + t];
    const int lane = t & 63, wid = t >> 6;
    int s = tot;
#pragma unroll
    for (int off = 1; off < 64; off <<= 1) {
        int tt = __shfl_up(s, off);
        if (lane >= off) s += tt;
    }
    if (lane == 63) swv[wid] = s;
    __syncthreads();
    if (t == 0) {
        int a = 0;
#pragma unroll
        for (int w = 0; w < 4; ++w) { int tt = swv[w]; swv[w] = a; a += tt; }
    }
    __syncthreads();
    int base = s - tot + swv[wid];
    if (t < NB) {
        bbase[t] = base;
        int run = base;
        for (int c = 0; c < NBLK; ++c) {
            int v = cnt[(size_t)c * NB + t];
            cnt[(size_t)c * NB + t] = run;
            run += v;
        }
    }
    if (t == 0) { bbase[NB] = E; rowptr[N] = E; }
}

// ---------------- k_bscatter: packed edges into bucket segments (LDS cursors)
__global__ __launch_bounds__(256) void k_bscatter(const int* __restrict__ eidx,
                                                  const int* __restrict__ cnt,
                                                  unsigned int* __restrict__ ebuf,
                                                  int E, int NB) {
    __shared__ int cur[256];
    const int tid = threadIdx.x;
    if (tid < NB) cur[tid] = cnt[(size_t)blockIdx.x * NB + tid];
    __syncthreads();
    const int base = blockIdx.x * CHUNK;
    for (int i = tid; i < CHUNK; i += 256) {
        int e = base + i;
        if (e < E) {
            int d = eidx[E + e];
            int s = eidx[e];
            int p = atomicAdd(&cur[d >> 9], 1);
            ebuf[p] = (unsigned int)s | ((unsigned int)(d & 511) << 17);
        }
    }
}

// ---------------- k_bfinal: per-bucket LDS hist + scan -> rowptr + colv
__global__ __launch_bounds__(256) void k_bfinal(const unsigned int* __restrict__ ebuf,
                                                const int* __restrict__ bbase,
                                                int* __restrict__ rowptr,
                                                int* __restrict__ colv, int N) {
    __shared__ int h[512];
    __shared__ int swv[4];
    const int b = blockIdx.x;
    const int tid = threadIdx.x;
    h[2 * tid] = 0;
    h[2 * tid + 1] = 0;
    __syncthreads();
    const int segb = bbase[b], sege = bbase[b + 1];
    for (int i = segb + tid; i < sege; i += 256)
        atomicAdd(&h[ebuf[i] >> 17], 1);
    __syncthreads();
    int a0 = h[2 * tid], a1 = h[2 * tid + 1];
    int ts = a0 + a1;
    const int lane = tid & 63, wid = tid >> 6;
    int s = ts;
#pragma unroll
    for (int off = 1; off < 64; off <<= 1) {
        int tt = __shfl_up(s, off);
        if (lane >= off) s += tt;
    }
    if (lane == 63) swv[wid] = s;
    __syncthreads();
    if (tid == 0) {
        int a = 0;
#pragma unroll
        for (int w = 0; w < 4; ++w) { int tt = swv[w]; swv[w] = a; a += tt; }
    }
    __syncthreads();
    int excl = s - ts + swv[wid];
    h[2 * tid] = excl;
    h[2 * tid + 1] = excl + a0;
    int node = b * 512 + 2 * tid;
    if (node < N) rowptr[node] = segb + excl;
    if (node + 1 < N) rowptr[node + 1] = segb + excl + a0;
    __syncthreads();
    for (int i = segb + tid; i < sege; i += 256) {
        unsigned int u = ebuf[i];
        int p = atomicAdd(&h[u >> 17], 1);
        colv[segb + p] = (int)(u & 0x1FFFFu);
    }
}

// -------------- gather-mean (bf16 x): 16 lanes/node, full occupancy
__global__ __launch_bounds__(256) void k_gather_bf(
        const uint2* __restrict__ xbf2, const int* __restrict__ rowptr,
        const int* __restrict__ colv, uint2* __restrict__ mh2, int N) {
    int t = blockIdx.x * 256 + threadIdx.x;
    int n = t >> 4;
    int l = t & 15;
    if (n >= N) return;
    int b = rowptr[n], e = rowptr[n + 1];
    float a0 = 0.f, a1 = 0.f, a2 = 0.f, a3 = 0.f;
    int p = b;
    for (; p + 4 <= e; p += 4) {
        int s0 = colv[p], s1 = colv[p + 1], s2 = colv[p + 2], s3 = colv[p + 3];
        uint2 v0 = xbf2[(size_t)s0 * 16 + l];
        uint2 v1 = xbf2[(size_t)s1 * 16 + l];
        uint2 v2 = xbf2[(size_t)s2 * 16 + l];
        uint2 v3 = xbf2[(size_t)s3 * 16 + l];
        a0 += bf2f((unsigned short)(v0.x & 0xFFFF)) + bf2f((unsigned short)(v1.x & 0xFFFF)) +
              bf2f((unsigned short)(v2.x & 0xFFFF)) + bf2f((unsigned short)(v3.x & 0xFFFF));
        a1 += bf2f((unsigned short)(v0.x >> 16)) + bf2f((unsigned short)(v1.x >> 16)) +
              bf2f((unsigned short)(v2.x >> 16)) + bf2f((unsigned short)(v3.x >> 16));
        a2 += bf2f((unsigned short)(v0.y & 0xFFFF)) + bf2f((unsigned short)(v1.y & 0xFFFF)) +
              bf2f((unsigned short)(v2.y & 0xFFFF)) + bf2f((unsigned short)(v3.y & 0xFFFF));
        a3 += bf2f((unsigned short)(v0.y >> 16)) + bf2f((unsigned short)(v1.y >> 16)) +
              bf2f((unsigned short)(v2.y >> 16)) + bf2f((unsigned short)(v3.y >> 16));
    }
    for (; p < e; ++p) {
        int s0 = colv[p];
        uint2 v0 = xbf2[(size_t)s0 * 16 + l];
        a0 += bf2f((unsigned short)(v0.x & 0xFFFF));
        a1 += bf2f((unsigned short)(v0.x >> 16));
        a2 += bf2f((unsigned short)(v0.y & 0xFFFF));
        a3 += bf2f((unsigned short)(v0.y >> 16));
    }
    float inv = 1.0f / fmaxf((float)(e - b), 1.0f);
    uint2 o;
    o.x = (unsigned int)f2bf(a0 * inv) | ((unsigned int)f2bf(a1 * inv) << 16);
    o.y = (unsigned int)f2bf(a2 * inv) | ((unsigned int)f2bf(a3 * inv) << 16);
    mh2[(size_t)n * 16 + l] = o;
}

// ------------------------- gather-mean (f32 x fallback, if ws too small)
__global__ __launch_bounds__(256) void k_gather_f32(
        const float4* __restrict__ x4, const int* __restrict__ rowptr,
        const int* __restrict__ colv, ushort4* __restrict__ mh, int N) {
    int t = blockIdx.x * 256 + threadIdx.x;
    int n = t >> 4;
    int l = t & 15;
    if (n >= N) return;
    int b = rowptr[n], e = rowptr[n + 1];
    float ax = 0.f, ay = 0.f, az = 0.f, aw = 0.f;
    int p = b;
    for (; p + 4 <= e; p += 4) {
        int s0 = colv[p], s1 = colv[p + 1], s2 = colv[p + 2], s3 = colv[p + 3];
        float4 v0 = x4[(size_t)s0 * 16 + l];
        float4 v1 = x4[(size_t)s1 * 16 + l];
        float4 v2 = x4[(size_t)s2 * 16 + l];
        float4 v3 = x4[(size_t)s3 * 16 + l];
        ax += (v0.x + v1.x) + (v2.x + v3.x);
        ay += (v0.y + v1.y) + (v2.y + v3.y);
        az += (v0.z + v1.z) + (v2.z + v3.z);
        aw += (v0.w + v1.w) + (v2.w + v3.w);
    }
    for (; p < e; ++p) {
        int s0 = colv[p];
        float4 v0 = x4[(size_t)s0 * 16 + l];
        ax += v0.x; ay += v0.y; az += v0.z; aw += v0.w;
    }
    float inv = 1.0f / fmaxf((float)(e - b), 1.0f);
    mh[(size_t)n * 16 + l] = make_ushort4(f2bf(ax * inv), f2bf(ay * inv),
                                          f2bf(az * inv), f2bf(aw * inv));
}

// --------- k_fused: MFMA [mean|x]@[Wl;Wr]^T + bl, L2norm, ReLU, BN partials.
// 256 nodes/block (4 tiles per wave). Root operand from xbf (bf16) when avail.
__global__ __launch_bounds__(256) void k_fused(
        const float* __restrict__ x,
        const unsigned short* __restrict__ xbf, int use_bf,
        const float* __restrict__ Wl, const float* __restrict__ bl,
        const float* __restrict__ Wr,
        unsigned short* __restrict__ mh,   // in: bf16 mean; out: bf16 h
        float* __restrict__ pstats, int N) {
    __shared__ float sRed[4][128];

    const int tid = threadIdx.x;
    const int wid = tid >> 6;
    const int lane = tid & 63;
    const int l15 = lane & 15;
    const int quad = lane >> 4;

    short8 bfrag[4][4];
#pragma unroll
    for (int c = 0; c < 4; ++c) {
#pragma unroll
        for (int f = 0; f < 4; ++f) {
            const int n = f * 16 + l15;
            const float* wsrc = (c < 2)
                ? (Wl + (size_t)n * 64 + c * 32 + quad * 8)
                : (Wr + (size_t)n * 64 + (c - 2) * 32 + quad * 8);
            float4 w0 = *(const float4*)wsrc;
            float4 w1 = *(const float4*)(wsrc + 4);
            union { short8 v; unsigned short u[8]; } pk;
            pk.u[0] = f2bf(w0.x); pk.u[1] = f2bf(w0.y);
            pk.u[2] = f2bf(w0.z); pk.u[3] = f2bf(w0.w);
            pk.u[4] = f2bf(w1.x); pk.u[5] = f2bf(w1.y);
            pk.u[6] = f2bf(w1.z); pk.u[7] = f2bf(w1.w);
            bfrag[c][f] = pk.v;
        }
    }

    float blv[4];
#pragma unroll
    for (int f = 0; f < 4; ++f) blv[f] = bl[f * 16 + l15];

    float psum[4] = {0.f, 0.f, 0.f, 0.f};
    float psq[4] = {0.f, 0.f, 0.f, 0.f};

    for (int t4 = 0; t4 < 4; ++t4) {
        const int tbase = blockIdx.x * 256 + wid * 64 + t4 * 16;
        const int mrow = tbase + l15;
        const int mld = (mrow < N) ? mrow : (N - 1);
        f32x4 acc[4] = {{0.f, 0.f, 0.f, 0.f}, {0.f, 0.f, 0.f, 0.f},
                        {0.f, 0.f, 0.f, 0.f}, {0.f, 0.f, 0.f, 0.f}};
#pragma unroll
        for (int c = 0; c < 2; ++c) {
            short8 a = *(const short8*)(mh + (size_t)mld * 64 + c * 32 + quad * 8);
#pragma unroll
            for (int f = 0; f < 4; ++f)
                acc[f] = __builtin_amdgcn_mfma_f32_16x16x32_bf16(a, bfrag[c][f], acc[f], 0, 0, 0);
        }
        if (use_bf) {
#pragma unroll
            for (int c = 0; c < 2; ++c) {
                short8 a = *(const short8*)(xbf + (size_t)mld * 64 + c * 32 + quad * 8);
#pragma unroll
                for (int f = 0; f < 4; ++f)
                    acc[f] = __builtin_amdgcn_mfma_f32_16x16x32_bf16(a, bfrag[c + 2][f], acc[f], 0, 0, 0);
            }
        } else {
#pragma unroll
            for (int c = 0; c < 2; ++c) {
                const float* xp = x + (size_t)mld * 64 + c * 32 + quad * 8;
                float4 a0 = *(const float4*)xp;
                float4 a1 = *(const float4*)(xp + 4);
                union { short8 v; unsigned short u[8]; } pk;
                pk.u[0] = f2bf(a0.x); pk.u[1] = f2bf(a0.y);
                pk.u[2] = f2bf(a0.z); pk.u[3] = f2bf(a0.w);
                pk.u[4] = f2bf(a1.x); pk.u[5] = f2bf(a1.y);
                pk.u[6] = f2bf(a1.z); pk.u[7] = f2bf(a1.w);
#pragma unroll
                for (int f = 0; f < 4; ++f)
                    acc[f] = __builtin_amdgcn_mfma_f32_16x16x32_bf16(pk.v, bfrag[c + 2][f], acc[f], 0, 0, 0);
            }
        }

#pragma unroll
        for (int reg = 0; reg < 4; ++reg) {
            const int node = tbase + quad * 4 + reg;
            float hv[4];
            float ss = 0.f;
#pragma unroll
            for (int f = 0; f < 4; ++f) {
                hv[f] = acc[f][reg] + blv[f];
                ss += hv[f] * hv[f];
            }
            ss += __shfl_xor(ss, 1);
            ss += __shfl_xor(ss, 2);
            ss += __shfl_xor(ss, 4);
            ss += __shfl_xor(ss, 8);
            float sc = 1.0f / fmaxf(sqrtf(ss), 1e-12f);
            if (node < N) {
#pragma unroll
                for (int f = 0; f < 4; ++f) {
                    float r = fmaxf(hv[f] * sc, 0.f);
                    unsigned short rb = f2bf(r);
                    float e = bf2f(rb);
                    mh[(size_t)node * 64 + f * 16 + l15] = rb;
                    psum[f] += e;
                    psq[f] += e * e;
                }
            }
        }
    }

#pragma unroll
    for (int f = 0; f < 4; ++f) {
        psum[f] += __shfl_xor(psum[f], 16);
        psum[f] += __shfl_xor(psum[f], 32);
        psq[f] += __shfl_xor(psq[f], 16);
        psq[f] += __shfl_xor(psq[f], 32);
    }
    if (lane < 16) {
#pragma unroll
        for (int f = 0; f < 4; ++f) {
            sRed[wid][f * 16 + l15] = psum[f];
            sRed[wid][64 + f * 16 + l15] = psq[f];
        }
    }
    __syncthreads();
    if (tid < 128) {
        float v = sRed[0][tid] + sRed[1][tid] + sRed[2][tid] + sRed[3][tid];
        pstats[(size_t)blockIdx.x * 128 + tid] = v;
    }
}

// ---------------------------------------------- reduce per-block BN partials
__global__ __launch_bounds__(64) void k_stats(const float* __restrict__ pstats,
                                              float* __restrict__ stats, int nblk) {
    int col = blockIdx.x;
    int l = threadIdx.x;
    float s = 0.f;
    for (int r = l; r < nblk; r += 64) s += pstats[(size_t)r * 128 + col];
    s += __shfl_xor(s, 1);
    s += __shfl_xor(s, 2);
    s += __shfl_xor(s, 4);
    s += __shfl_xor(s, 8);
    s += __shfl_xor(s, 16);
    s += __shfl_xor(s, 32);
    if (l == 0) stats[col] = s;
}

// ---------------------------------------------------------------- BN-fold + FC
__global__ __launch_bounds__(256) void k_out(
        const unsigned short* __restrict__ h, const float* __restrict__ stats,
        const float* __restrict__ gamma, const float* __restrict__ beta,
        const float* __restrict__ Wfc, const float* __restrict__ bfc,
        float* __restrict__ out, int N) {
    __shared__ float sWm[64 * 16];
    __shared__ float sShift[64];
    __shared__ float sBase[16];
    const int tid = threadIdx.x;
    const float invN = 1.0f / (float)N;
    if (tid < 64) {
        float mu = stats[tid] * invN;
        float var = stats[64 + tid] * invN - mu * mu;
        float sc = gamma[tid] / sqrtf(var + 1e-5f);
        sShift[tid] = beta[tid] - mu * sc;
#pragma unroll
        for (int c = 0; c < 16; ++c) sWm[tid * 16 + c] = Wfc[c * 64 + tid] * sc;
    }
    __syncthreads();
    if (tid < 16) {
        float b = bfc[tid];
#pragma unroll
        for (int j = 0; j < 64; ++j) b += sShift[j] * Wfc[tid * 64 + j];
        sBase[tid] = b;
    }
    __syncthreads();
    int g = blockIdx.x * 256 + tid;
    int n = g >> 4;
    int c = g & 15;
    if (n >= N) return;
    const ushort4* h4 = (const ushort4*)(h + (size_t)n * 64);
    float acc = sBase[c];
#pragma unroll
    for (int jq = 0; jq < 16; ++jq) {
        ushort4 v = h4[jq];
        acc += bf2f(v.x) * sWm[(jq * 4 + 0) * 16 + c];
        acc += bf2f(v.y) * sWm[(jq * 4 + 1) * 16 + c];
        acc += bf2f(v.z) * sWm[(jq * 4 + 2) * 16 + c];
        acc += bf2f(v.w) * sWm[(jq * 4 + 3) * 16 + c];
    }
    out[(size_t)n * 16 + c] = acc;
}

extern "C" void kernel_launch(void* const* d_in, const int* in_sizes, int n_in,
                              void* d_out, int out_size, void* d_ws, size_t ws_size,
                              hipStream_t stream) {
    const int* eidx = (const int*)d_in[0];
    const float* x = (const float*)d_in[1];
    const float* Wl = (const float*)d_in[2];
    const float* bl = (const float*)d_in[3];
    const float* Wr = (const float*)d_in[4];
    const float* gamma = (const float*)d_in[5];
    const float* beta = (const float*)d_in[6];
    const float* Wfc = (const float*)d_in[7];
    const float* bfc = (const float*)d_in[8];
    float* out = (float*)d_out;

    const int E = in_sizes[0] / 2;
    const int N = in_sizes[1] / 64;
    const int NB = (N + 511) >> 9;               // <=256 for N<=131072
    const int NBLK = (E + CHUNK - 1) / CHUNK;    // <=256 for E<=2.09M
    const int fb2 = (N + 255) / 256;             // k_fused blocks
    const int n4 = N * 16;

    // layout (4B words):
    int* cnt = (int*)d_ws;                                     // NBLK*NB
    int* bbase = cnt + (size_t)NBLK * NB;                      // NB+1
    int* rowptr = bbase + NB + 1;                              // N+1
    float* pstats = (float*)(rowptr + N + 1);                  // fb2*128
    float* stats = pstats + (size_t)fb2 * 128;                 // 128
    int* colv = (int*)(stats + 128);                           // E
    unsigned int* ebuf = (unsigned int*)(colv + E);            // E
    unsigned short* mh = (unsigned short*)(ebuf + E);          // N*64 bf16
    unsigned short* xbf = mh + (size_t)N * 64;                 // N*64 bf16 opt

    size_t need_bf = (size_t)((char*)(xbf + (size_t)N * 64) - (char*)d_ws);
    const int use_bf = (ws_size >= need_bf) ? 1 : 0;

    int cbl = use_bf ? (n4 + 255) / 256 : 0;
    k_prep<<<NBLK + cbl, 256, 0, stream>>>(eidx, cnt, (const float4*)x,
                                           (ushort4*)xbf, E, NB, NBLK, n4, use_bf);
    k_bscan<<<1, 256, 0, stream>>>(cnt, bbase, rowptr, NBLK, NB, N, E);
    k_bscatter<<<NBLK, 256, 0, stream>>>(eidx, cnt, ebuf, E, NB);
    k_bfinal<<<NB, 256, 0, stream>>>(ebuf, bbase, rowptr, colv, N);

    int gblocks = (int)(((size_t)N * 16 + 255) / 256);
    if (use_bf) {
        k_gather_bf<<<gblocks, 256, 0, stream>>>((const uint2*)xbf, rowptr, colv,
                                                 (uint2*)mh, N);
    } else {
        k_gather_f32<<<gblocks, 256, 0, stream>>>((const float4*)x, rowptr, colv,
                                                  (ushort4*)mh, N);
    }

    k_fused<<<fb2, 256, 0, stream>>>(x, xbf, use_bf, Wl, bl, Wr, mh, pstats, N);
    k_stats<<<128, 64, 0, stream>>>(pstats, stats, fb2);

    int oblocks = (int)(((size_t)N * 16 + 255) / 256);
    k_out<<<oblocks, 256, 0, stream>>>(mh, stats, gamma, beta, Wfc, bfc, out, N);
}

// Round 12
// 213.186 us; speedup vs baseline: 1.6039x; 1.2125x over previous
//
#include <hip/hip_runtime.h>
#include <hip/hip_bf16.h>

// SAGEConv(mean), 9-dispatch pipeline, zero global atomics:
//   k_prep    = bucket histogram (LDS atomics) + x->bf16 cast, fused
//   k_scanbkt = per-bucket coalesced scan over chunks (rel offsets + btot)
//   k_bscanB  = 1-block scan of bucket totals -> bbase, sentinels
//   k_bscatter= scatter packed (dst&511)<<17|src into bucket segments
//   k_bfinal  = per-bucket LDS counting sort -> rowptr + colv
//   k_gather  = 16-lanes/node CSR gather-mean (6250 blocks: TLP is king)
//   k_fused   = MFMA [mean|x]@[Wl;Wr]^T + L2norm + ReLU + BN partials
//   k_stats / k_out
// N=100000, E=1200000, F=H=64, C=16.
//
// Lessons: R4/R5/R7/R8 — device-scope atomics run at the shared coherence
// point (~24.5 G atomics/s); only LDS atomics are cheap. R10 — never shrink
// the random gather's grid (needs ~25k waves of TLP). R11 — never serialize
// a scan into one block to save a launch: 147 strided loads/thread = 52us;
// a 5us launch is cheaper than a latency chain.
// cnt layout: [bucket][chunk] so per-bucket scan reads are coalesced.

typedef __attribute__((ext_vector_type(8))) short short8;   // 8 bf16
typedef __attribute__((ext_vector_type(4))) float f32x4;

__device__ __forceinline__ unsigned short f2bf(float f) {
    unsigned int u = __builtin_bit_cast(unsigned int, f);
    u += 0x7FFFu + ((u >> 16) & 1u);
    return (unsigned short)(u >> 16);
}
__device__ __forceinline__ float bf2f(unsigned short s) {
    return __builtin_bit_cast(float, ((unsigned int)s) << 16);
}

#define CHUNK 8192

// ---------------- k_prep: blocks [0,NBLK) = bucket hist; rest = x->bf16 cast
__global__ __launch_bounds__(256) void k_prep(const int* __restrict__ eidx,
                                              int* __restrict__ cnt,
                                              const float4* __restrict__ x4,
                                              ushort4* __restrict__ xbf,
                                              int E, int NB, int NBLK,
                                              int n4, int do_x) {
    __shared__ int lh[256];
    const int tid = threadIdx.x;
    if ((int)blockIdx.x < NBLK) {
        lh[tid] = 0;
        __syncthreads();
        const int base = blockIdx.x * CHUNK;
        for (int i = tid; i < CHUNK; i += 256) {
            int e = base + i;
            if (e < E) atomicAdd(&lh[eidx[E + e] >> 9], 1);
        }
        __syncthreads();
        if (tid < NB) cnt[(size_t)tid * NBLK + blockIdx.x] = lh[tid];
    } else if (do_x) {
        int t = ((int)blockIdx.x - NBLK) * 256 + tid;
        if (t < n4) {
            float4 v = x4[t];
            xbf[t] = make_ushort4(f2bf(v.x), f2bf(v.y), f2bf(v.z), f2bf(v.w));
        }
    }
}

// -------- k_scanbkt: one block per bucket; coalesced scan over its chunk row
__global__ __launch_bounds__(256) void k_scanbkt(int* __restrict__ cnt,
                                                 int* __restrict__ btot,
                                                 int NBLK) {
    __shared__ int swv[4];
    const int b = blockIdx.x;
    const int t = threadIdx.x;
    int v = (t < NBLK) ? cnt[(size_t)b * NBLK + t] : 0;
    const int lane = t & 63, wid = t >> 6;
    int s = v;
#pragma unroll
    for (int off = 1; off < 64; off <<= 1) {
        int tt = __shfl_up(s, off);
        if (lane >= off) s += tt;
    }
    if (lane == 63) swv[wid] = s;
    __syncthreads();
    if (t == 0) {
        int a = 0;
#pragma unroll
        for (int w = 0; w < 4; ++w) { int tt = swv[w]; swv[w] = a; a += tt; }
    }
    __syncthreads();
    int excl = s - v + swv[wid];
    if (t < NBLK) cnt[(size_t)b * NBLK + t] = excl;   // relative offset
    if (t == 255) btot[b] = swv[3] + s;               // bucket total
}

// -------- k_bscanB: 1 block; scan bucket totals -> bbase; sentinels
__global__ __launch_bounds__(256) void k_bscanB(const int* __restrict__ btot,
                                                int* __restrict__ bbase,
                                                int* __restrict__ rowptr,
                                                int NB, int N, int E) {
    __shared__ int swv[4];
    const int t = threadIdx.x;
    int v = (t < NB) ? btot[t] : 0;
    const int lane = t & 63, wid = t >> 6;
    int s = v;
#pragma unroll
    for (int off = 1; off < 64; off <<= 1) {
        int tt = __shfl_up(s, off);
        if (lane >= off) s += tt;
    }
    if (lane == 63) swv[wid] = s;
    __syncthreads();
    if (t == 0) {
        int a = 0;
#pragma unroll
        for (int w = 0; w < 4; ++w) { int tt = swv[w]; swv[w] = a; a += tt; }
    }
    __syncthreads();
    if (t < NB) bbase[t] = s - v + swv[wid];
    if (t == 0) { bbase[NB] = E; rowptr[N] = E; }
}

// ---------------- k_bscatter: packed edges into bucket segments (LDS cursors)
__global__ __launch_bounds__(256) void k_bscatter(const int* __restrict__ eidx,
                                                  const int* __restrict__ cnt,
                                                  const int* __restrict__ bbase,
                                                  unsigned int* __restrict__ ebuf,
                                                  int E, int NB, int NBLK) {
    __shared__ int cur[256];
    const int tid = threadIdx.x;
    if (tid < NB)
        cur[tid] = bbase[tid] + cnt[(size_t)tid * NBLK + blockIdx.x];
    __syncthreads();
    const int base = blockIdx.x * CHUNK;
    for (int i = tid; i < CHUNK; i += 256) {
        int e = base + i;
        if (e < E) {
            int d = eidx[E + e];
            int s = eidx[e];
            int p = atomicAdd(&cur[d >> 9], 1);
            ebuf[p] = (unsigned int)s | ((unsigned int)(d & 511) << 17);
        }
    }
}

// ---------------- k_bfinal: per-bucket LDS hist + scan -> rowptr + colv
__global__ __launch_bounds__(256) void k_bfinal(const unsigned int* __restrict__ ebuf,
                                                const int* __restrict__ bbase,
                                                int* __restrict__ rowptr,
                                                int* __restrict__ colv, int N) {
    __shared__ int h[512];
    __shared__ int swv[4];
    const int b = blockIdx.x;
    const int tid = threadIdx.x;
    h[2 * tid] = 0;
    h[2 * tid + 1] = 0;
    __syncthreads();
    const int segb = bbase[b], sege = bbase[b + 1];
    for (int i = segb + tid; i < sege; i += 256)
        atomicAdd(&h[ebuf[i] >> 17], 1);
    __syncthreads();
    int a0 = h[2 * tid], a1 = h[2 * tid + 1];
    int ts = a0 + a1;
    const int lane = tid & 63, wid = tid >> 6;
    int s = ts;
#pragma unroll
    for (int off = 1; off < 64; off <<= 1) {
        int tt = __shfl_up(s, off);
        if (lane >= off) s += tt;
    }
    if (lane == 63) swv[wid] = s;
    __syncthreads();
    if (tid == 0) {
        int a = 0;
#pragma unroll
        for (int w = 0; w < 4; ++w) { int tt = swv[w]; swv[w] = a; a += tt; }
    }
    __syncthreads();
    int excl = s - ts + swv[wid];
    h[2 * tid] = excl;
    h[2 * tid + 1] = excl + a0;
    int node = b * 512 + 2 * tid;
    if (node < N) rowptr[node] = segb + excl;
    if (node + 1 < N) rowptr[node + 1] = segb + excl + a0;
    __syncthreads();
    for (int i = segb + tid; i < sege; i += 256) {
        unsigned int u = ebuf[i];
        int p = atomicAdd(&h[u >> 17], 1);
        colv[segb + p] = (int)(u & 0x1FFFFu);
    }
}

// -------------- gather-mean (bf16 x): 16 lanes/node, full occupancy
__global__ __launch_bounds__(256) void k_gather_bf(
        const uint2* __restrict__ xbf2, const int* __restrict__ rowptr,
        const int* __restrict__ colv, uint2* __restrict__ mh2, int N) {
    int t = blockIdx.x * 256 + threadIdx.x;
    int n = t >> 4;
    int l = t & 15;
    if (n >= N) return;
    int b = rowptr[n], e = rowptr[n + 1];
    float a0 = 0.f, a1 = 0.f, a2 = 0.f, a3 = 0.f;
    int p = b;
    for (; p + 4 <= e; p += 4) {
        int s0 = colv[p], s1 = colv[p + 1], s2 = colv[p + 2], s3 = colv[p + 3];
        uint2 v0 = xbf2[(size_t)s0 * 16 + l];
        uint2 v1 = xbf2[(size_t)s1 * 16 + l];
        uint2 v2 = xbf2[(size_t)s2 * 16 + l];
        uint2 v3 = xbf2[(size_t)s3 * 16 + l];
        a0 += bf2f((unsigned short)(v0.x & 0xFFFF)) + bf2f((unsigned short)(v1.x & 0xFFFF)) +
              bf2f((unsigned short)(v2.x & 0xFFFF)) + bf2f((unsigned short)(v3.x & 0xFFFF));
        a1 += bf2f((unsigned short)(v0.x >> 16)) + bf2f((unsigned short)(v1.x >> 16)) +
              bf2f((unsigned short)(v2.x >> 16)) + bf2f((unsigned short)(v3.x >> 16));
        a2 += bf2f((unsigned short)(v0.y & 0xFFFF)) + bf2f((unsigned short)(v1.y & 0xFFFF)) +
              bf2f((unsigned short)(v2.y & 0xFFFF)) + bf2f((unsigned short)(v3.y & 0xFFFF));
        a3 += bf2f((unsigned short)(v0.y >> 16)) + bf2f((unsigned short)(v1.y >> 16)) +
              bf2f((unsigned short)(v2.y >> 16)) + bf2f((unsigned short)(v3.y >> 16));
    }
    for (; p < e; ++p) {
        int s0 = colv[p];
        uint2 v0 = xbf2[(size_t)s0 * 16 + l];
        a0 += bf2f((unsigned short)(v0.x & 0xFFFF));
        a1 += bf2f((unsigned short)(v0.x >> 16));
        a2 += bf2f((unsigned short)(v0.y & 0xFFFF));
        a3 += bf2f((unsigned short)(v0.y >> 16));
    }
    float inv = 1.0f / fmaxf((float)(e - b), 1.0f);
    uint2 o;
    o.x = (unsigned int)f2bf(a0 * inv) | ((unsigned int)f2bf(a1 * inv) << 16);
    o.y = (unsigned int)f2bf(a2 * inv) | ((unsigned int)f2bf(a3 * inv) << 16);
    mh2[(size_t)n * 16 + l] = o;
}

// ------------------------- gather-mean (f32 x fallback, if ws too small)
__global__ __launch_bounds__(256) void k_gather_f32(
        const float4* __restrict__ x4, const int* __restrict__ rowptr,
        const int* __restrict__ colv, ushort4* __restrict__ mh, int N) {
    int t = blockIdx.x * 256 + threadIdx.x;
    int n = t >> 4;
    int l = t & 15;
    if (n >= N) return;
    int b = rowptr[n], e = rowptr[n + 1];
    float ax = 0.f, ay = 0.f, az = 0.f, aw = 0.f;
    int p = b;
    for (; p + 4 <= e; p += 4) {
        int s0 = colv[p], s1 = colv[p + 1], s2 = colv[p + 2], s3 = colv[p + 3];
        float4 v0 = x4[(size_t)s0 * 16 + l];
        float4 v1 = x4[(size_t)s1 * 16 + l];
        float4 v2 = x4[(size_t)s2 * 16 + l];
        float4 v3 = x4[(size_t)s3 * 16 + l];
        ax += (v0.x + v1.x) + (v2.x + v3.x);
        ay += (v0.y + v1.y) + (v2.y + v3.y);
        az += (v0.z + v1.z) + (v2.z + v3.z);
        aw += (v0.w + v1.w) + (v2.w + v3.w);
    }
    for (; p < e; ++p) {
        int s0 = colv[p];
        float4 v0 = x4[(size_t)s0 * 16 + l];
        ax += v0.x; ay += v0.y; az += v0.z; aw += v0.w;
    }
    float inv = 1.0f / fmaxf((float)(e - b), 1.0f);
    mh[(size_t)n * 16 + l] = make_ushort4(f2bf(ax * inv), f2bf(ay * inv),
                                          f2bf(az * inv), f2bf(aw * inv));
}

// --------- k_fused: MFMA [mean|x]@[Wl;Wr]^T + bl, L2norm, ReLU, BN partials.
// 256 nodes/block (4 tiles per wave). Root operand from xbf (bf16) when avail.
__global__ __launch_bounds__(256) void k_fused(
        const float* __restrict__ x,
        const unsigned short* __restrict__ xbf, int use_bf,
        const float* __restrict__ Wl, const float* __restrict__ bl,
        const float* __restrict__ Wr,
        unsigned short* __restrict__ mh,   // in: bf16 mean; out: bf16 h
        float* __restrict__ pstats, int N) {
    __shared__ float sRed[4][128];

    const int tid = threadIdx.x;
    const int wid = tid >> 6;
    const int lane = tid & 63;
    const int l15 = lane & 15;
    const int quad = lane >> 4;

    short8 bfrag[4][4];
#pragma unroll
    for (int c = 0; c < 4; ++c) {
#pragma unroll
        for (int f = 0; f < 4; ++f) {
            const int n = f * 16 + l15;
            const float* wsrc = (c < 2)
                ? (Wl + (size_t)n * 64 + c * 32 + quad * 8)
                : (Wr + (size_t)n * 64 + (c - 2) * 32 + quad * 8);
            float4 w0 = *(const float4*)wsrc;
            float4 w1 = *(const float4*)(wsrc + 4);
            union { short8 v; unsigned short u[8]; } pk;
            pk.u[0] = f2bf(w0.x); pk.u[1] = f2bf(w0.y);
            pk.u[2] = f2bf(w0.z); pk.u[3] = f2bf(w0.w);
            pk.u[4] = f2bf(w1.x); pk.u[5] = f2bf(w1.y);
            pk.u[6] = f2bf(w1.z); pk.u[7] = f2bf(w1.w);
            bfrag[c][f] = pk.v;
        }
    }

    float blv[4];
#pragma unroll
    for (int f = 0; f < 4; ++f) blv[f] = bl[f * 16 + l15];

    float psum[4] = {0.f, 0.f, 0.f, 0.f};
    float psq[4] = {0.f, 0.f, 0.f, 0.f};

    for (int t4 = 0; t4 < 4; ++t4) {
        const int tbase = blockIdx.x * 256 + wid * 64 + t4 * 16;
        const int mrow = tbase + l15;
        const int mld = (mrow < N) ? mrow : (N - 1);
        f32x4 acc[4] = {{0.f, 0.f, 0.f, 0.f}, {0.f, 0.f, 0.f, 0.f},
                        {0.f, 0.f, 0.f, 0.f}, {0.f, 0.f, 0.f, 0.f}};
#pragma unroll
        for (int c = 0; c < 2; ++c) {
            short8 a = *(const short8*)(mh + (size_t)mld * 64 + c * 32 + quad * 8);
#pragma unroll
            for (int f = 0; f < 4; ++f)
                acc[f] = __builtin_amdgcn_mfma_f32_16x16x32_bf16(a, bfrag[c][f], acc[f], 0, 0, 0);
        }
        if (use_bf) {
#pragma unroll
            for (int c = 0; c < 2; ++c) {
                short8 a = *(const short8*)(xbf + (size_t)mld * 64 + c * 32 + quad * 8);
#pragma unroll
                for (int f = 0; f < 4; ++f)
                    acc[f] = __builtin_amdgcn_mfma_f32_16x16x32_bf16(a, bfrag[c + 2][f], acc[f], 0, 0, 0);
            }
        } else {
#pragma unroll
            for (int c = 0; c < 2; ++c) {
                const float* xp = x + (size_t)mld * 64 + c * 32 + quad * 8;
                float4 a0 = *(const float4*)xp;
                float4 a1 = *(const float4*)(xp + 4);
                union { short8 v; unsigned short u[8]; } pk;
                pk.u[0] = f2bf(a0.x); pk.u[1] = f2bf(a0.y);
                pk.u[2] = f2bf(a0.z); pk.u[3] = f2bf(a0.w);
                pk.u[4] = f2bf(a1.x); pk.u[5] = f2bf(a1.y);
                pk.u[6] = f2bf(a1.z); pk.u[7] = f2bf(a1.w);
#pragma unroll
                for (int f = 0; f < 4; ++f)
                    acc[f] = __builtin_amdgcn_mfma_f32_16x16x32_bf16(pk.v, bfrag[c + 2][f], acc[f], 0, 0, 0);
            }
        }

#pragma unroll
        for (int reg = 0; reg < 4; ++reg) {
            const int node = tbase + quad * 4 + reg;
            float hv[4];
            float ss = 0.f;
#pragma unroll
            for (int f = 0; f < 4; ++f) {
                hv[f] = acc[f][reg] + blv[f];
                ss += hv[f] * hv[f];
            }
            ss += __shfl_xor(ss, 1);
            ss += __shfl_xor(ss, 2);
            ss += __shfl_xor(ss, 4);
            ss += __shfl_xor(ss, 8);
            float sc = 1.0f / fmaxf(sqrtf(ss), 1e-12f);
            if (node < N) {
#pragma unroll
                for (int f = 0; f < 4; ++f) {
                    float r = fmaxf(hv[f] * sc, 0.f);
                    unsigned short rb = f2bf(r);
                    float e = bf2f(rb);
                    mh[(size_t)node * 64 + f * 16 + l15] = rb;
                    psum[f] += e;
                    psq[f] += e * e;
                }
            }
        }
    }

#pragma unroll
    for (int f = 0; f < 4; ++f) {
        psum[f] += __shfl_xor(psum[f], 16);
        psum[f] += __shfl_xor(psum[f], 32);
        psq[f] += __shfl_xor(psq[f], 16);
        psq[f] += __shfl_xor(psq[f], 32);
    }
    if (lane < 16) {
#pragma unroll
        for (int f = 0; f < 4; ++f) {
            sRed[wid][f * 16 + l15] = psum[f];
            sRed[wid][64 + f * 16 + l15] = psq[f];
        }
    }
    __syncthreads();
    if (tid < 128) {
        float v = sRed[0][tid] + sRed[1][tid] + sRed[2][tid] + sRed[3][tid];
        pstats[(size_t)blockIdx.x * 128 + tid] = v;
    }
}

// ---------------------------------------------- reduce per-block BN partials
__global__ __launch_bounds__(64) void k_stats(const float* __restrict__ pstats,
                                              float* __restrict__ stats, int nblk) {
    int col = blockIdx.x;
    int l = threadIdx.x;
    float s = 0.f;
    for (int r = l; r < nblk; r += 64) s += pstats[(size_t)r * 128 + col];
    s += __shfl_xor(s, 1);
    s += __shfl_xor(s, 2);
    s += __shfl_xor(s, 4);
    s += __shfl_xor(s, 8);
    s += __shfl_xor(s, 16);
    s += __shfl_xor(s, 32);
    if (l == 0) stats[col] = s;
}

// ---------------------------------------------------------------- BN-fold + FC
__global__ __launch_bounds__(256) void k_out(
        const unsigned short* __restrict__ h, const float* __restrict__ stats,
        const float* __restrict__ gamma, const float* __restrict__ beta,
        const float* __restrict__ Wfc, const float* __restrict__ bfc,
        float* __restrict__ out, int N) {
    __shared__ float sWm[64 * 16];
    __shared__ float sShift[64];
    __shared__ float sBase[16];
    const int tid = threadIdx.x;
    const float invN = 1.0f / (float)N;
    if (tid < 64) {
        float mu = stats[tid] * invN;
        float var = stats[64 + tid] * invN - mu * mu;
        float sc = gamma[tid] / sqrtf(var + 1e-5f);
        sShift[tid] = beta[tid] - mu * sc;
#pragma unroll
        for (int c = 0; c < 16; ++c) sWm[tid * 16 + c] = Wfc[c * 64 + tid] * sc;
    }
    __syncthreads();
    if (tid < 16) {
        float b = bfc[tid];
#pragma unroll
        for (int j = 0; j < 64; ++j) b += sShift[j] * Wfc[tid * 64 + j];
        sBase[tid] = b;
    }
    __syncthreads();
    int g = blockIdx.x * 256 + tid;
    int n = g >> 4;
    int c = g & 15;
    if (n >= N) return;
    const ushort4* h4 = (const ushort4*)(h + (size_t)n * 64);
    float acc = sBase[c];
#pragma unroll
    for (int jq = 0; jq < 16; ++jq) {
        ushort4 v = h4[jq];
        acc += bf2f(v.x) * sWm[(jq * 4 + 0) * 16 + c];
        acc += bf2f(v.y) * sWm[(jq * 4 + 1) * 16 + c];
        acc += bf2f(v.z) * sWm[(jq * 4 + 2) * 16 + c];
        acc += bf2f(v.w) * sWm[(jq * 4 + 3) * 16 + c];
    }
    out[(size_t)n * 16 + c] = acc;
}

extern "C" void kernel_launch(void* const* d_in, const int* in_sizes, int n_in,
                              void* d_out, int out_size, void* d_ws, size_t ws_size,
                              hipStream_t stream) {
    const int* eidx = (const int*)d_in[0];
    const float* x = (const float*)d_in[1];
    const float* Wl = (const float*)d_in[2];
    const float* bl = (const float*)d_in[3];
    const float* Wr = (const float*)d_in[4];
    const float* gamma = (const float*)d_in[5];
    const float* beta = (const float*)d_in[6];
    const float* Wfc = (const float*)d_in[7];
    const float* bfc = (const float*)d_in[8];
    float* out = (float*)d_out;

    const int E = in_sizes[0] / 2;
    const int N = in_sizes[1] / 64;
    const int NB = (N + 511) >> 9;               // <=256 for N<=131072
    const int NBLK = (E + CHUNK - 1) / CHUNK;    // <=256 for E<=2.09M
    const int fb2 = (N + 255) / 256;             // k_fused blocks
    const int n4 = N * 16;

    // layout (4B words):
    int* cnt = (int*)d_ws;                                     // NB*NBLK
    int* btot = cnt + (size_t)NB * NBLK;                       // NB
    int* bbase = btot + NB;                                    // NB+1
    int* rowptr = bbase + NB + 1;                              // N+1
    float* pstats = (float*)(rowptr + N + 1);                  // fb2*128
    float* stats = pstats + (size_t)fb2 * 128;                 // 128
    int* colv = (int*)(stats + 128);                           // E
    unsigned int* ebuf = (unsigned int*)(colv + E);            // E
    unsigned short* mh = (unsigned short*)(ebuf + E);          // N*64 bf16
    unsigned short* xbf = mh + (size_t)N * 64;                 // N*64 bf16 opt

    size_t need_bf = (size_t)((char*)(xbf + (size_t)N * 64) - (char*)d_ws);
    const int use_bf = (ws_size >= need_bf) ? 1 : 0;

    int cbl = use_bf ? (n4 + 255) / 256 : 0;
    k_prep<<<NBLK + cbl, 256, 0, stream>>>(eidx, cnt, (const float4*)x,
                                           (ushort4*)xbf, E, NB, NBLK, n4, use_bf);
    k_scanbkt<<<NB, 256, 0, stream>>>(cnt, btot, NBLK);
    k_bscanB<<<1, 256, 0, stream>>>(btot, bbase, rowptr, NB, N, E);
    k_bscatter<<<NBLK, 256, 0, stream>>>(eidx, cnt, bbase, ebuf, E, NB, NBLK);
    k_bfinal<<<NB, 256, 0, stream>>>(ebuf, bbase, rowptr, colv, N);

    int gblocks = (int)(((size_t)N * 16 + 255) / 256);
    if (use_bf) {
        k_gather_bf<<<gblocks, 256, 0, stream>>>((const uint2*)xbf, rowptr, colv,
                                                 (uint2*)mh, N);
    } else {
        k_gather_f32<<<gblocks, 256, 0, stream>>>((const float4*)x, rowptr, colv,
                                                  (ushort4*)mh, N);
    }

    k_fused<<<fb2, 256, 0, stream>>>(x, xbf, use_bf, Wl, bl, Wr, mh, pstats, N);
    k_stats<<<128, 64, 0, stream>>>(pstats, stats, fb2);

    int oblocks = (int)(((size_t)N * 16 + 255) / 256);
    k_out<<<oblocks, 256, 0, stream>>>(mh, stats, gamma, beta, Wfc, bfc, out, N);
}